// Round 1
// baseline (390.136 us; speedup 1.0000x reference)
//
#include <hip/hip_runtime.h>
#include <hip/hip_bf16.h>

// Problem: out[4096,4096] = x[4096,4096]fp32 @ dequant(int4 W)[4096,4096] + bias
// K = 4096, groupsize 128 (32 groups). qweight[512,4096] int32: row kk packs
// k = kk*8+j in nibble j. qzeros[32,512]: word n>>3 packs col n in nibble n&7.
//
// Algorithm: out = sum_g s[g,n] * sum_{k in g} (x_hi + x_lo)[m,k] * (w[k,n]-z[g,n])
//   - (w-z) integers in [-16,14]: EXACT in bf16
//   - x split into two truncated bf16 (hi/lo) -> ~2^-16 relative error
//   - group-partial S in separate MFMA accumulator; folded with scale per group
//     (S restarted via C=zero operand on first MFMA of each group: no clears)

#define K_DIM 4096
#define N_DIM 4096
#define M_DIM 4096
#define BM 128
#define BN 128
#define BK 64

typedef __attribute__((ext_vector_type(8))) short s8v;      // 8 bf16 = 4 VGPR
typedef __attribute__((ext_vector_type(4))) float f4v;
typedef __attribute__((ext_vector_type(4))) unsigned int u4v;
typedef __attribute__((ext_vector_type(2))) unsigned int u2v;
typedef __attribute__((ext_vector_type(4))) float float4v;

typedef __attribute__((address_space(3))) void LDSV;
typedef const __attribute__((address_space(1))) void GLBV;

__device__ __forceinline__ void glds16(const void* g, void* l) {
    // async global->LDS, 16B/lane, dest = uniform base + lane*16
    __builtin_amdgcn_global_load_lds((GLBV*)g, (LDSV*)l, 16, 0, 0);
}

// ---------------- prologue: split x (fp32) into truncated bf16 hi + lo ------
__global__ __launch_bounds__(256) void split_x(const float* __restrict__ x,
                                               unsigned short* __restrict__ xh,
                                               unsigned short* __restrict__ xl,
                                               int n4) {
    int idx = blockIdx.x * 256 + threadIdx.x;
    int stride = gridDim.x * 256;
    for (int i = idx; i < n4; i += stride) {
        float4v v = ((const float4v*)x)[i];
        unsigned int hb[4], lb[4];
#pragma unroll
        for (int j = 0; j < 4; j++) {
            unsigned int b = __float_as_uint(v[j]);
            unsigned int h = b & 0xFFFF0000u;   // truncated bf16 (as f32 bits)
            hb[j] = h;
            float res = v[j] - __uint_as_float(h);
            lb[j] = __float_as_uint(res);
        }
        u2v hv = {(hb[0] >> 16) | hb[1], (hb[2] >> 16) | hb[3]};
        u2v lv = {(lb[0] >> 16) | (lb[1] & 0xFFFF0000u),
                  (lb[2] >> 16) | (lb[3] & 0xFFFF0000u)};
        ((u2v*)xh)[i] = hv;
        ((u2v*)xl)[i] = lv;
    }
}

// ---------------- main GEMM --------------------------------------------------
__global__ __launch_bounds__(256, 2) void gemm_q4(
    const unsigned short* __restrict__ xh, const unsigned short* __restrict__ xl,
    const int* __restrict__ qw, const int* __restrict__ qz,
    const float* __restrict__ scales, const float* __restrict__ bias,
    float* __restrict__ out) {
    // LDS: A-hi / A-lo [128][64] bf16, W [128 n][64 k] bf16; 48 KB total.
    // byte layout per row: 128 B; XOR-swizzle byte ^= ((row&7)<<4) -> 2-way free
    __shared__ __align__(16) unsigned short AH[BM * BK];
    __shared__ __align__(16) unsigned short AL[BM * BK];
    __shared__ __align__(16) unsigned short WT[BN * BK];

    const int tid = threadIdx.x;
    const int lane = tid & 63;
    const int wid = tid >> 6;

    // bijective XCD swizzle: 1024 wgs, 8 XCDs -> each XCD owns 128 contiguous
    // tile-ids = 4 row-panels x 32 col-tiles (A-panel L2 reuse)
    const int bid = blockIdx.x;
    const int wg = ((bid & 7) << 7) + (bid >> 3);
    const int bm = (wg >> 5) << 7;
    const int bn = (wg & 31) << 7;

    const int wr = ((wid >> 1) & 1) << 6;  // wave row origin: 0/64
    const int wc = (wid & 1) << 6;         // wave col origin: 0/64

    f4v acc[4][4];
    f4v S[4][4];
    const f4v z4 = {0.f, 0.f, 0.f, 0.f};
#pragma unroll
    for (int i = 0; i < 4; i++)
#pragma unroll
        for (int j = 0; j < 4; j++) acc[i][j] = z4;

    // ---- A staging (global_load_lds, pre-swizzled source) ----
    // wave w covers rows [w*32, w*32+32), 4 insts x (8 rows, 1KB) per buffer.
    // lane -> row = base + (lane>>3); phys k-slot = (lane&7)*16; since
    // row&7 == lane>>3, source element k-offset = ((lane&7)^(lane>>3))*8.
    const int arow = lane >> 3;
    const int aswz = ((lane & 7) ^ arow) << 3;  // element offset, 0..56
    const size_t a_gbase = (size_t)(bm + wid * 32 + arow) * K_DIM + aswz;
    unsigned short* ah_l = &AH[(wid * 32) * BK];
    unsigned short* al_l = &AL[(wid * 32) * BK];

    // ---- W staging: thread owns col n_loc, 4 of 8 kk-rows per tile ----
    const int n_loc = tid & 127;
    const int kq0 = (tid >> 7) << 2;  // 0 or 4
    const int ng = bn + n_loc;
    const int* qz_p = qz + (ng >> 3);
    const int z_sh = (ng & 7) * 4;
    const int* qw_base = qw + kq0 * N_DIM + ng;
    const int wswz = (n_loc & 7) << 4;

    // ---- per-lane fragment coords (16x16x32 bf16 MFMA) ----
    // A: row = lane&15, k = (lane>>4)*8 + j ; B: col = lane&15, same k
    const int frow = lane & 15;
    const int fk16 = (lane >> 4) << 4;  // k byte offset within row

    char* AHb = (char*)AH;
    char* ALb = (char*)AL;
    char* WTb = (char*)WT;

    // prefetch W words for kt=0
    int q[4];
    {
        const int* p = qw_base;
#pragma unroll
        for (int r = 0; r < 4; r++) q[r] = p[r * N_DIM];
    }

#pragma unroll 1
    for (int g = 0; g < 32; ++g) {
        // scales for end-of-group fold (one per n-subtile; col = lane&15)
        float sc[4];
        const float* sp = scales + (size_t)g * N_DIM + bn + wc + frow;
#pragma unroll
        for (int ni = 0; ni < 4; ni++) sc[ni] = sp[ni * 16];
        // zero point for this thread's column: zc = 128 + (z+1)
        const float zc = (float)(129 + ((qz_p[(size_t)g * 512] >> z_sh) & 15));

#pragma unroll
        for (int sub = 0; sub < 2; ++sub) {
            const int kt = g * 2 + sub;
            __syncthreads();  // LDS free (previous tile computed)

            // A hi/lo: 8 async 1KB loads per wave
            const unsigned short* gh = xh + a_gbase + kt * BK;
            const unsigned short* gl = xl + a_gbase + kt * BK;
#pragma unroll
            for (int i = 0; i < 4; i++) {
                glds16(gh + i * 8 * K_DIM, ah_l + i * 8 * BK);
                glds16(gl + i * 8 * K_DIM, al_l + i * 8 * BK);
            }

            // W unpack: nibble -> f32 via exponent trick, exact bf16 by >>16
#pragma unroll
            for (int r = 0; r < 4; r++) {
                const unsigned int qq = (unsigned int)q[r];
                unsigned int fb[8];
#pragma unroll
                for (int j = 0; j < 8; j++) {
                    float f = __uint_as_float(0x43000000u |
                                              (((qq >> (4 * j)) & 15u) << 16)) - zc;
                    fb[j] = __float_as_uint(f);  // low 16 bits are zero (exact int)
                }
                u4v dv = {(fb[0] >> 16) | (fb[1] & 0xFFFF0000u),
                          (fb[2] >> 16) | (fb[3] & 0xFFFF0000u),
                          (fb[4] >> 16) | (fb[5] & 0xFFFF0000u),
                          (fb[6] >> 16) | (fb[7] & 0xFFFF0000u)};
                const int kbyte = (kq0 + r) << 4;
                *(u4v*)(WTb + n_loc * 128 + (kbyte ^ wswz)) = dv;
            }

            // prefetch W words for next tile (hidden under compute)
            if (kt < 63) {
                const int* p = qw_base + (kt + 1) * 8 * N_DIM;
#pragma unroll
                for (int r = 0; r < 4; r++) q[r] = p[r * N_DIM];
            }

            __syncthreads();  // drains glds (vmcnt0) + ds_writes

            // compute: 2 k-steps of K=32
#pragma unroll
            for (int ks = 0; ks < 2; ++ks) {
                s8v ahf[4], alf[4], bf[4];
                const int kb = (ks << 6) | fk16;
#pragma unroll
                for (int mi = 0; mi < 4; mi++) {
                    const int r = wr + mi * 16 + frow;
                    const int off = r * 128 + (kb ^ ((r & 7) << 4));
                    ahf[mi] = *(const s8v*)(AHb + off);
                    alf[mi] = *(const s8v*)(ALb + off);
                }
#pragma unroll
                for (int ni = 0; ni < 4; ni++) {
                    const int r = wc + ni * 16 + frow;
                    bf[ni] = *(const s8v*)(WTb + r * 128 + (kb ^ ((r & 7) << 4)));
                }
#pragma unroll
                for (int mi = 0; mi < 4; mi++)
#pragma unroll
                    for (int ni = 0; ni < 4; ni++) {
                        f4v c0 = (sub == 0 && ks == 0) ? z4 : S[mi][ni];
                        S[mi][ni] = __builtin_amdgcn_mfma_f32_16x16x32_bf16(
                            ahf[mi], bf[ni], c0, 0, 0, 0);
                        S[mi][ni] = __builtin_amdgcn_mfma_f32_16x16x32_bf16(
                            alf[mi], bf[ni], S[mi][ni], 0, 0, 0);
                    }
            }
        }
        // fold group partial into final accumulator with per-column scale
#pragma unroll
        for (int mi = 0; mi < 4; mi++)
#pragma unroll
            for (int ni = 0; ni < 4; ni++) acc[mi][ni] += sc[ni] * S[mi][ni];
    }

    // epilogue: C layout col = lane&15, row = (lane>>4)*4 + reg
    const int col0 = bn + wc + frow;
    const int row00 = bm + wr + ((lane >> 4) << 2);
#pragma unroll
    for (int ni = 0; ni < 4; ni++) {
        const float bv = bias[col0 + ni * 16];
#pragma unroll
        for (int mi = 0; mi < 4; mi++) {
            f4v v = acc[mi][ni];
#pragma unroll
            for (int r2 = 0; r2 < 4; r2++)
                out[(size_t)(row00 + mi * 16 + r2) * N_DIM + col0 + ni * 16] =
                    v[r2] + bv;
        }
    }
}

// ---------------- fallback (ws too small): naive but correct ----------------
__global__ __launch_bounds__(256) void naive_q4(
    const float* __restrict__ x, const int* __restrict__ qw,
    const int* __restrict__ qz, const float* __restrict__ scales,
    const float* __restrict__ bias, float* __restrict__ out) {
    const int n = (blockIdx.x & 63) * 64 + (threadIdx.x & 63);
    const int m = (blockIdx.x >> 6) * 4 + (threadIdx.x >> 6);
    const float* xr = x + (size_t)m * K_DIM;
    float acc = 0.f;
    for (int g = 0; g < 32; ++g) {
        const float s = scales[g * N_DIM + n];
        const int z = ((qz[g * 512 + (n >> 3)] >> ((n & 7) * 4)) & 15) + 1;
        float gs = 0.f;
        for (int kk = 0; kk < 16; ++kk) {
            const int q = qw[(g * 16 + kk) * N_DIM + n];
            const float* xp = xr + g * 128 + kk * 8;
#pragma unroll
            for (int j = 0; j < 8; j++)
                gs += xp[j] * (float)(((q >> (4 * j)) & 15) - z);
        }
        acc += s * gs;
    }
    out[(size_t)m * N_DIM + n] = acc + bias[n];
}

extern "C" void kernel_launch(void* const* d_in, const int* in_sizes, int n_in,
                              void* d_out, int out_size, void* d_ws,
                              size_t ws_size, hipStream_t stream) {
    const float* x = (const float*)d_in[0];
    const int* qw = (const int*)d_in[1];
    const int* qz = (const int*)d_in[2];
    const float* sc = (const float*)d_in[3];
    const float* bias = (const float*)d_in[4];
    float* out = (float*)d_out;

    const size_t need = (size_t)2 * M_DIM * K_DIM * sizeof(unsigned short);  // 64 MB
    if (ws_size >= need) {
        unsigned short* xh = (unsigned short*)d_ws;
        unsigned short* xl = xh + (size_t)M_DIM * K_DIM;
        split_x<<<2048, 256, 0, stream>>>(x, xh, xl, M_DIM * K_DIM / 4);
        gemm_q4<<<(M_DIM / BM) * (N_DIM / BN), 256, 0, stream>>>(xh, xl, qw, qz,
                                                                 sc, bias, out);
    } else {
        naive_q4<<<(M_DIM / 4) * (N_DIM / 64), 256, 0, stream>>>(x, qw, qz, sc,
                                                                 bias, out);
    }
}